// Round 4
// baseline (7892.149 us; speedup 1.0000x reference)
//
#include <hip/hip_runtime.h>
#include <hip/hip_bf16.h>

#define B_   64
#define S_   1024
#define D_   512
#define H_   512
#define NWG  256    // 1 wave per WG -> 1 per CU; 4 row-cohorts x 64 col-slices
#define NCS  64     // column slices
#define HCW  8      // h-columns per col-slice
#define NT   64

typedef __attribute__((ext_vector_type(8))) short short8;
typedef __attribute__((ext_vector_type(4))) float f32x4;

// Swizzled byte offset into the LDS W tile: [gc][k] bf16, row = 2048 B.
__device__ __forceinline__ int wl_byte(int gc, int k) {
  return ((gc << 11) + (k << 1)) ^ ((gc & 7) << 4);
}
__device__ __forceinline__ float sigm(float v) { return 1.0f / (1.0f + __expf(-v)); }
__device__ __forceinline__ float tanh_(float v) { return 1.0f - 2.0f / (__expf(2.0f * v) + 1.0f); }
__device__ __forceinline__ short f2bf(float f) {
  __hip_bfloat16 h = __float2bfloat16(f);
  short s;
  __builtin_memcpy(&s, &h, 2);
  return s;
}

union U128 { unsigned long long u[2]; unsigned int w[4]; short8 s; };

// Cache-bypassing (LLC-coherent) 16B store. Single transaction -> tag+data atomic.
__device__ __forceinline__ void store_b128_sys(void* p, short8 v) {
  asm volatile("global_store_dwordx4 %0, %1, off sc0 sc1" :: "v"(p), "v"(v) : "memory");
}

__global__ __launch_bounds__(NT, 1) void lstm_persist(
    const float* __restrict__ xg,
    const float* __restrict__ Wf, const float* __restrict__ bfv,
    const float* __restrict__ Wi, const float* __restrict__ biv,
    const float* __restrict__ Wc, const float* __restrict__ bcv,
    const float* __restrict__ Wo, const float* __restrict__ bov,
    float* __restrict__ out,
    char* __restrict__ hbc,            // [2][64 rows][64 cs][2 quads][16B] tagged records
    unsigned int* __restrict__ flags)  // [4 cohorts][64 cs] u32: "tag t drained"
{
  __shared__ short Wl[32 * 1024];    // 64 KB: W slice, [gc][k] bf16, swizzled

  const int tid  = threadIdx.x;
  const int wg   = blockIdx.x;
  const int cs   = wg >> 2;          // column slice 0..63
  const int rc   = wg & 3;           // row cohort 0..3 (16 batch rows)
  const int lane = tid;              // single wave

  // ---- one-time: stage this WG's W slice (transposed to [gc][k], bf16) ----
  {
    const float* Wg4[4] = {Wf, Wi, Wc, Wo};
    const int gc  = tid >> 1;        // 0..31
    const int seg = tid & 1;         // k half of 512
    const float* Wsrc = Wg4[gc >> 3];
    const int col = cs * HCW + (gc & 7);
    for (int kk = 0; kk < 512; ++kk) {
      const int k = seg * 512 + kk;
      *(short*)((char*)Wl + wl_byte(gc, k)) = f2bf(Wsrc[(size_t)k * H_ + col]);
    }
  }

  // Transposed-C lane mapping: C'[gatecol][row]; lane&15 = batch row,
  // (lane>>4)*4+reg = gatecol. q=0,2 -> cols 0-3; q=1,3 -> cols 4-7.
  const int q    = lane >> 4;        // 0..3
  const int rr   = lane & 15;        // batch row within wave tile
  const int c0   = (q & 1) << 2;     // col-quad base within slice's 8 cols
  const int colq = cs * HCW + c0;    // global col-quad base
  float bF4[4], bI4[4], bG4[4], bO4[4];
#pragma unroll
  for (int r = 0; r < 4; ++r) {
    bF4[r] = bfv[colq + r]; bI4[r] = biv[colq + r];
    bG4[r] = bcv[colq + r]; bO4[r] = bov[colq + r];
  }

  __syncthreads();                   // Wl ready (single wave; effectively free)

  // A/B fragment addressing: index = lane&15, 8 consecutive k at ks*32+q*8.
  const int rowb = (rc << 4) + rr;   // this lane's batch row
  const int kb8  = q << 3;
  const float* xbase = xg + (size_t)rowb * S_ * D_;

  float cst[4] = {0.f, 0.f, 0.f, 0.f};   // cell state: 4 cols of row rowb

  for (int t = 0; t < S_; ++t) {
    const char* hrd = hbc + (t & 1) * (B_ * NCS * 32);
    char*       hwr = hbc + ((t + 1) & 1) * (B_ * NCS * 32);

    f32x4 acc0 = {0.f, 0.f, 0.f, 0.f};   // gatecols [0,16):  f | i
    f32x4 acc1 = {0.f, 0.f, 0.f, 0.f};   // gatecols [16,32): g | o

    const float* xr = xbase + (size_t)t * D_;

    // ---- x-part first (no cross-WG dependency; hides prior stores' drain) ----
#pragma unroll 4
    for (int ks = 0; ks < 16; ++ks) {
      const int kx = ks * 32 + kb8;
      f32x4 f0 = *(const f32x4*)(xr + kx);
      f32x4 f1 = *(const f32x4*)(xr + kx + 4);
      short8 a;
#pragma unroll
      for (int j = 0; j < 4; ++j) { a[j] = f2bf(f0[j]); a[4 + j] = f2bf(f1[j]); }
      const int kw = 512 + kx;
      short8 b0 = *(const short8*)((const char*)Wl + wl_byte(lane & 15, kw));
      short8 b1 = *(const short8*)((const char*)Wl + wl_byte(16 + (lane & 15), kw));
      acc0 = __builtin_amdgcn_mfma_f32_16x16x32_bf16(b0, a, acc0, 0, 0, 0);
      acc1 = __builtin_amdgcn_mfma_f32_16x16x32_bf16(b1, a, acc1, 0, 0, 0);
    }

    // ---- publish our tag-t flag (records stored last iteration, drained by
    //      the vmcnt(0); the drain is hidden behind the x-part above), then
    //      cheap-poll the 64 producer flags of our cohort: 1 dword per lane,
    //      2 cache lines per wave per attempt (vs 64 KB with tag-polling). ----
    if (t > 0) {
      asm volatile("s_waitcnt vmcnt(0)" ::: "memory");
      if (lane == 0) {
        __hip_atomic_store(&flags[(rc << 6) + cs], (unsigned int)t,
                           __ATOMIC_RELAXED, __HIP_MEMORY_SCOPE_SYSTEM);
      }
      const unsigned int tgt = (unsigned int)t;
      unsigned int v;
      do {
        v = __hip_atomic_load(&flags[(rc << 6) + lane], __ATOMIC_RELAXED,
                              __HIP_MEMORY_SCOPE_SYSTEM);
      } while (!__all((int)(v >= tgt)));
      asm volatile("" ::: "memory");
    }

    // ---- h-part: one-shot bulk load of tagged records (flags guarantee
    //      drained data; tag-check retry kept as a zero-cost safety net).
    //      Lane needs records (rowb, cs=ks*4+q, quad 0/1) -> one base,
    //      strided 128B, all 32 in one asm block + vmcnt(0). ----
    {
      const char* rb = hrd + (((rowb << 6) + q) << 5);
      const unsigned int tgt = (unsigned int)t;
      U128 rc0, rc1, rc2, rc3, rc4, rc5, rc6, rc7,
           rc8, rc9, rc10, rc11, rc12, rc13, rc14, rc15,
           rc16, rc17, rc18, rc19, rc20, rc21, rc22, rc23,
           rc24, rc25, rc26, rc27, rc28, rc29, rc30, rc31;
      while (true) {
        asm volatile(
          "global_load_dwordx4 %[r0], %[p], off sc0 sc1\n\t"
          "global_load_dwordx4 %[r1], %[p], off offset:16 sc0 sc1\n\t"
          "global_load_dwordx4 %[r2], %[p], off offset:128 sc0 sc1\n\t"
          "global_load_dwordx4 %[r3], %[p], off offset:144 sc0 sc1\n\t"
          "global_load_dwordx4 %[r4], %[p], off offset:256 sc0 sc1\n\t"
          "global_load_dwordx4 %[r5], %[p], off offset:272 sc0 sc1\n\t"
          "global_load_dwordx4 %[r6], %[p], off offset:384 sc0 sc1\n\t"
          "global_load_dwordx4 %[r7], %[p], off offset:400 sc0 sc1\n\t"
          "global_load_dwordx4 %[r8], %[p], off offset:512 sc0 sc1\n\t"
          "global_load_dwordx4 %[r9], %[p], off offset:528 sc0 sc1\n\t"
          "global_load_dwordx4 %[r10], %[p], off offset:640 sc0 sc1\n\t"
          "global_load_dwordx4 %[r11], %[p], off offset:656 sc0 sc1\n\t"
          "global_load_dwordx4 %[r12], %[p], off offset:768 sc0 sc1\n\t"
          "global_load_dwordx4 %[r13], %[p], off offset:784 sc0 sc1\n\t"
          "global_load_dwordx4 %[r14], %[p], off offset:896 sc0 sc1\n\t"
          "global_load_dwordx4 %[r15], %[p], off offset:912 sc0 sc1\n\t"
          "global_load_dwordx4 %[r16], %[p], off offset:1024 sc0 sc1\n\t"
          "global_load_dwordx4 %[r17], %[p], off offset:1040 sc0 sc1\n\t"
          "global_load_dwordx4 %[r18], %[p], off offset:1152 sc0 sc1\n\t"
          "global_load_dwordx4 %[r19], %[p], off offset:1168 sc0 sc1\n\t"
          "global_load_dwordx4 %[r20], %[p], off offset:1280 sc0 sc1\n\t"
          "global_load_dwordx4 %[r21], %[p], off offset:1296 sc0 sc1\n\t"
          "global_load_dwordx4 %[r22], %[p], off offset:1408 sc0 sc1\n\t"
          "global_load_dwordx4 %[r23], %[p], off offset:1424 sc0 sc1\n\t"
          "global_load_dwordx4 %[r24], %[p], off offset:1536 sc0 sc1\n\t"
          "global_load_dwordx4 %[r25], %[p], off offset:1552 sc0 sc1\n\t"
          "global_load_dwordx4 %[r26], %[p], off offset:1664 sc0 sc1\n\t"
          "global_load_dwordx4 %[r27], %[p], off offset:1680 sc0 sc1\n\t"
          "global_load_dwordx4 %[r28], %[p], off offset:1792 sc0 sc1\n\t"
          "global_load_dwordx4 %[r29], %[p], off offset:1808 sc0 sc1\n\t"
          "global_load_dwordx4 %[r30], %[p], off offset:1920 sc0 sc1\n\t"
          "global_load_dwordx4 %[r31], %[p], off offset:1936 sc0 sc1\n\t"
          "s_waitcnt vmcnt(0)"
          : [r0]"=&v"(rc0.s), [r1]"=&v"(rc1.s), [r2]"=&v"(rc2.s),
            [r3]"=&v"(rc3.s), [r4]"=&v"(rc4.s), [r5]"=&v"(rc5.s),
            [r6]"=&v"(rc6.s), [r7]"=&v"(rc7.s), [r8]"=&v"(rc8.s),
            [r9]"=&v"(rc9.s), [r10]"=&v"(rc10.s), [r11]"=&v"(rc11.s),
            [r12]"=&v"(rc12.s), [r13]"=&v"(rc13.s), [r14]"=&v"(rc14.s),
            [r15]"=&v"(rc15.s), [r16]"=&v"(rc16.s), [r17]"=&v"(rc17.s),
            [r18]"=&v"(rc18.s), [r19]"=&v"(rc19.s), [r20]"=&v"(rc20.s),
            [r21]"=&v"(rc21.s), [r22]"=&v"(rc22.s), [r23]"=&v"(rc23.s),
            [r24]"=&v"(rc24.s), [r25]"=&v"(rc25.s), [r26]"=&v"(rc26.s),
            [r27]"=&v"(rc27.s), [r28]"=&v"(rc28.s), [r29]"=&v"(rc29.s),
            [r30]"=&v"(rc30.s), [r31]"=&v"(rc31.s)
          : [p]"v"(rb)
          : "memory");
        const unsigned int bad =
            (rc0.w[2] ^ tgt) | (rc1.w[2] ^ tgt) | (rc2.w[2] ^ tgt) |
            (rc3.w[2] ^ tgt) | (rc4.w[2] ^ tgt) | (rc5.w[2] ^ tgt) |
            (rc6.w[2] ^ tgt) | (rc7.w[2] ^ tgt) | (rc8.w[2] ^ tgt) |
            (rc9.w[2] ^ tgt) | (rc10.w[2] ^ tgt) | (rc11.w[2] ^ tgt) |
            (rc12.w[2] ^ tgt) | (rc13.w[2] ^ tgt) | (rc14.w[2] ^ tgt) |
            (rc15.w[2] ^ tgt) | (rc16.w[2] ^ tgt) | (rc17.w[2] ^ tgt) |
            (rc18.w[2] ^ tgt) | (rc19.w[2] ^ tgt) | (rc20.w[2] ^ tgt) |
            (rc21.w[2] ^ tgt) | (rc22.w[2] ^ tgt) | (rc23.w[2] ^ tgt) |
            (rc24.w[2] ^ tgt) | (rc25.w[2] ^ tgt) | (rc26.w[2] ^ tgt) |
            (rc27.w[2] ^ tgt) | (rc28.w[2] ^ tgt) | (rc29.w[2] ^ tgt) |
            (rc30.w[2] ^ tgt) | (rc31.w[2] ^ tgt);
        if (__all((int)(bad == 0u))) break;
      }

#define HSTEP(KS, RA, RB)                                                      \
      {                                                                        \
        U128 a_; a_.u[0] = RA.u[0]; a_.u[1] = RB.u[0];                         \
        const int k0_ = (KS) * 32 + kb8;                                       \
        short8 b0_ = *(const short8*)((const char*)Wl + wl_byte(lane & 15, k0_)); \
        short8 b1_ = *(const short8*)((const char*)Wl + wl_byte(16 + (lane & 15), k0_)); \
        acc0 = __builtin_amdgcn_mfma_f32_16x16x32_bf16(b0_, a_.s, acc0, 0, 0, 0); \
        acc1 = __builtin_amdgcn_mfma_f32_16x16x32_bf16(b1_, a_.s, acc1, 0, 0, 0); \
      }
      HSTEP(0, rc0, rc1)   HSTEP(1, rc2, rc3)   HSTEP(2, rc4, rc5)
      HSTEP(3, rc6, rc7)   HSTEP(4, rc8, rc9)   HSTEP(5, rc10, rc11)
      HSTEP(6, rc12, rc13) HSTEP(7, rc14, rc15) HSTEP(8, rc16, rc17)
      HSTEP(9, rc18, rc19) HSTEP(10, rc20, rc21) HSTEP(11, rc22, rc23)
      HSTEP(12, rc24, rc25) HSTEP(13, rc26, rc27) HSTEP(14, rc28, rc29)
      HSTEP(15, rc30, rc31)
#undef HSTEP
    }

    // ---- epilogue: exchange f<->i / g<->o halves across lane^32 ----
    f32x4 x0, x1;
#pragma unroll
    for (int j = 0; j < 4; ++j) {
      x0[j] = __shfl_xor(acc0[j], 32);
      x1[j] = __shfl_xor(acc1[j], 32);
    }
    const bool lo = (q < 2);
    float hv[4];
#pragma unroll
    for (int r = 0; r < 4; ++r) {
      const float sF = (lo ? acc0[r] : x0[r]) + bF4[r];
      const float sI = (lo ? x0[r] : acc0[r]) + bI4[r];
      const float sG = (lo ? acc1[r] : x1[r]) + bG4[r];
      const float sO = (lo ? x1[r] : acc1[r]) + bO4[r];
      const float fg = sigm(sF);
      const float ig = sigm(sI);
      const float gg = tanh_(sG);
      const float og = sigm(sO);
      const float cn = cst[r] * fg + gg * ig;
      cst[r] = cn;
      hv[r] = og * tanh_(cn);
    }

    if (lo) {
      // ---- tagged record broadcast FIRST (visibility-critical):
      //      {4 bf16 cols, tag=t+1, pad} in one atomic 16B store ----
      if (t < S_ - 1) {
        unsigned int l32 = (unsigned int)(unsigned short)f2bf(hv[0])
                         | ((unsigned int)(unsigned short)f2bf(hv[1]) << 16);
        unsigned int h32 = (unsigned int)(unsigned short)f2bf(hv[2])
                         | ((unsigned int)(unsigned short)f2bf(hv[3]) << 16);
        U128 u;
        u.w[0] = l32; u.w[1] = h32;
        u.w[2] = (unsigned int)(t + 1); u.w[3] = 0u;
        store_b128_sys(hwr + (((rowb << 6) + cs) << 5) + (q << 4), u.s);
      }

      // ---- out: one 16B store per lane (4 consecutive cols of row rowb) ----
      f32x4 hv4;
#pragma unroll
      for (int r = 0; r < 4; ++r) hv4[r] = hv[r];
      *(f32x4*)(out + (size_t)rowb * ((size_t)S_ * H_) + (size_t)t * H_ + colq) = hv4;
      if (t == S_ - 1) {
        f32x4 c4;
#pragma unroll
        for (int r = 0; r < 4; ++r) c4[r] = cst[r];
        *(f32x4*)(out + (size_t)B_ * S_ * H_ + (size_t)rowb * H_ + colq) = hv4;
        *(f32x4*)(out + (size_t)B_ * S_ * H_ + (size_t)B_ * H_
                      + (size_t)rowb * H_ + colq) = c4;
      }
    }
    // Flag for tag t+1 goes out at the top of the next iteration, after the
    // x-part has hidden the store-drain latency.
  }
}

extern "C" void kernel_launch(void* const* d_in, const int* in_sizes, int n_in,
                              void* d_out, int out_size, void* d_ws, size_t ws_size,
                              hipStream_t stream) {
  (void)in_sizes; (void)n_in; (void)out_size; (void)ws_size;
  const float* x  = (const float*)d_in[0];
  const float* Wf = (const float*)d_in[1];
  const float* bf = (const float*)d_in[2];
  const float* Wi = (const float*)d_in[3];
  const float* bi = (const float*)d_in[4];
  const float* Wc = (const float*)d_in[5];
  const float* bc = (const float*)d_in[6];
  const float* Wo = (const float*)d_in[7];
  const float* bo = (const float*)d_in[8];
  float* out = (float*)d_out;

  unsigned int* flags = (unsigned int*)d_ws;   // 1 KB used: [4][64] u32
  char* hbc = (char*)d_ws + 4096;              // 256 KB tagged h records

  // zero flags + both record parities: tag 0 == h_0 == 0; captured in the
  // graph, so every replay starts from a clean state.
  hipMemsetAsync(d_ws, 0, 4096 + 2 * B_ * NCS * 32, stream);

  lstm_persist<<<dim3(NWG), dim3(NT), 0, stream>>>(
      x, Wf, bf, Wi, bi, Wc, bc, Wo, bo, out, hbc, flags);
}

// Round 5
// 6041.903 us; speedup vs baseline: 1.3062x; 1.3062x over previous
//
#include <hip/hip_runtime.h>
#include <hip/hip_bf16.h>

#define B_   64
#define S_   1024
#define D_   512
#define H_   512
#define NWG  256    // 1 wave per WG -> 1 per CU; 4 row-cohorts x 64 col-slices
#define NCS  64     // column slices
#define HCW  8      // h-columns per col-slice
#define NT   64

typedef __attribute__((ext_vector_type(8))) short short8;
typedef __attribute__((ext_vector_type(4))) float f32x4;

// Swizzled byte offset into the LDS W tile: [gc][k] bf16, row = 2048 B.
__device__ __forceinline__ int wl_byte(int gc, int k) {
  return ((gc << 11) + (k << 1)) ^ ((gc & 7) << 4);
}
__device__ __forceinline__ float sigm(float v) { return 1.0f / (1.0f + __expf(-v)); }
__device__ __forceinline__ float tanh_(float v) { return 1.0f - 2.0f / (__expf(2.0f * v) + 1.0f); }
__device__ __forceinline__ short f2bf(float f) {
  __hip_bfloat16 h = __float2bfloat16(f);
  short s;
  __builtin_memcpy(&s, &h, 2);
  return s;
}

union U128 { unsigned long long u[2]; unsigned int w[4]; short8 s; };

// Cache-bypassing (LLC-coherent) 16B store. Single transaction -> tag+data atomic.
__device__ __forceinline__ void store_b128_sys(void* p, short8 v) {
  asm volatile("global_store_dwordx4 %0, %1, off sc0 sc1" :: "v"(p), "v"(v) : "memory");
}

__global__ __launch_bounds__(NT, 1) void lstm_persist(
    const float* __restrict__ xg,
    const float* __restrict__ Wf, const float* __restrict__ bfv,
    const float* __restrict__ Wi, const float* __restrict__ biv,
    const float* __restrict__ Wc, const float* __restrict__ bcv,
    const float* __restrict__ Wo, const float* __restrict__ bov,
    float* __restrict__ out,
    char* __restrict__ hbc,            // [2][64 rows][64 cs][2 quads][16B] tagged records
    unsigned int* __restrict__ flags)  // [4 cohorts][64 cs] u32: "records tag t drained"
{
  __shared__ short Wl[32 * 1024];    // 64 KB: W slice, [gc][k] bf16, swizzled

  const int tid  = threadIdx.x;
  const int wg   = blockIdx.x;
  const int cs   = wg >> 2;          // column slice 0..63
  const int rc   = wg & 3;           // row cohort 0..3 (16 batch rows)
  const int lane = tid;              // single wave

  // ---- one-time: stage this WG's W slice (transposed to [gc][k], bf16) ----
  {
    const float* Wg4[4] = {Wf, Wi, Wc, Wo};
    const int gc  = tid >> 1;        // 0..31
    const int seg = tid & 1;         // k half of 512
    const float* Wsrc = Wg4[gc >> 3];
    const int col = cs * HCW + (gc & 7);
    for (int kk = 0; kk < 512; ++kk) {
      const int k = seg * 512 + kk;
      *(short*)((char*)Wl + wl_byte(gc, k)) = f2bf(Wsrc[(size_t)k * H_ + col]);
    }
  }

  // Transposed-C lane mapping: C'[gatecol][row]; lane&15 = batch row,
  // (lane>>4)*4+reg = gatecol. q=0,2 -> cols 0-3; q=1,3 -> cols 4-7.
  const int q    = lane >> 4;        // 0..3
  const int rr   = lane & 15;        // batch row within wave tile
  const int c0   = (q & 1) << 2;     // col-quad base within slice's 8 cols
  const int colq = cs * HCW + c0;    // global col-quad base
  float bF4[4], bI4[4], bG4[4], bO4[4];
#pragma unroll
  for (int r = 0; r < 4; ++r) {
    bF4[r] = bfv[colq + r]; bI4[r] = biv[colq + r];
    bG4[r] = bcv[colq + r]; bO4[r] = bov[colq + r];
  }

  __syncthreads();                   // Wl ready (single wave; effectively free)

  // A/B fragment addressing: index = lane&15, 8 consecutive k at ks*32+q*8.
  const int rowb = (rc << 4) + rr;   // this lane's batch row
  const int kb8  = q << 3;
  const float* xbase = xg + (size_t)rowb * S_ * D_;

  float cst[4] = {0.f, 0.f, 0.f, 0.f};   // cell state: 4 cols of row rowb

  for (int t = 0; t < S_; ++t) {
    const char* hrd = hbc + (t & 1) * (B_ * NCS * 32);
    char*       hwr = hbc + ((t + 1) & 1) * (B_ * NCS * 32);

    f32x4 acc0 = {0.f, 0.f, 0.f, 0.f};   // gatecols [0,16):  f | i
    f32x4 acc1 = {0.f, 0.f, 0.f, 0.f};   // gatecols [16,32): g | o

    const float* xr = xbase + (size_t)t * D_;

    // ---- x-part first (no cross-WG dependency) ----
#pragma unroll 4
    for (int ks = 0; ks < 16; ++ks) {
      const int kx = ks * 32 + kb8;
      f32x4 f0 = *(const f32x4*)(xr + kx);
      f32x4 f1 = *(const f32x4*)(xr + kx + 4);
      short8 a;
#pragma unroll
      for (int j = 0; j < 4; ++j) { a[j] = f2bf(f0[j]); a[4 + j] = f2bf(f1[j]); }
      const int kw = 512 + kx;
      short8 b0 = *(const short8*)((const char*)Wl + wl_byte(lane & 15, kw));
      short8 b1 = *(const short8*)((const char*)Wl + wl_byte(16 + (lane & 15), kw));
      acc0 = __builtin_amdgcn_mfma_f32_16x16x32_bf16(b0, a, acc0, 0, 0, 0);
      acc1 = __builtin_amdgcn_mfma_f32_16x16x32_bf16(b1, a, acc1, 0, 0, 0);
    }

    // ---- h-part: speculative bulk load of tagged records (detection == data
    //      load when it hits). On a stale attempt, spin on the DENSE flag
    //      array (1 dword/lane, 2 cache lines/wave per attempt, ~4x faster
    //      retry period than re-issuing the 64KB bulk load), then re-issue
    //      the bulk load once; tags then provably match (cohort-flag
    //      induction bounds buffer reuse). ----
    {
      const char* rb = hrd + (((rowb << 6) + q) << 5);
      const unsigned int tgt = (unsigned int)t;
      U128 rc0, rc1, rc2, rc3, rc4, rc5, rc6, rc7,
           rc8, rc9, rc10, rc11, rc12, rc13, rc14, rc15,
           rc16, rc17, rc18, rc19, rc20, rc21, rc22, rc23,
           rc24, rc25, rc26, rc27, rc28, rc29, rc30, rc31;
      while (true) {
        asm volatile(
          "global_load_dwordx4 %[r0], %[p], off sc0 sc1\n\t"
          "global_load_dwordx4 %[r1], %[p], off offset:16 sc0 sc1\n\t"
          "global_load_dwordx4 %[r2], %[p], off offset:128 sc0 sc1\n\t"
          "global_load_dwordx4 %[r3], %[p], off offset:144 sc0 sc1\n\t"
          "global_load_dwordx4 %[r4], %[p], off offset:256 sc0 sc1\n\t"
          "global_load_dwordx4 %[r5], %[p], off offset:272 sc0 sc1\n\t"
          "global_load_dwordx4 %[r6], %[p], off offset:384 sc0 sc1\n\t"
          "global_load_dwordx4 %[r7], %[p], off offset:400 sc0 sc1\n\t"
          "global_load_dwordx4 %[r8], %[p], off offset:512 sc0 sc1\n\t"
          "global_load_dwordx4 %[r9], %[p], off offset:528 sc0 sc1\n\t"
          "global_load_dwordx4 %[r10], %[p], off offset:640 sc0 sc1\n\t"
          "global_load_dwordx4 %[r11], %[p], off offset:656 sc0 sc1\n\t"
          "global_load_dwordx4 %[r12], %[p], off offset:768 sc0 sc1\n\t"
          "global_load_dwordx4 %[r13], %[p], off offset:784 sc0 sc1\n\t"
          "global_load_dwordx4 %[r14], %[p], off offset:896 sc0 sc1\n\t"
          "global_load_dwordx4 %[r15], %[p], off offset:912 sc0 sc1\n\t"
          "global_load_dwordx4 %[r16], %[p], off offset:1024 sc0 sc1\n\t"
          "global_load_dwordx4 %[r17], %[p], off offset:1040 sc0 sc1\n\t"
          "global_load_dwordx4 %[r18], %[p], off offset:1152 sc0 sc1\n\t"
          "global_load_dwordx4 %[r19], %[p], off offset:1168 sc0 sc1\n\t"
          "global_load_dwordx4 %[r20], %[p], off offset:1280 sc0 sc1\n\t"
          "global_load_dwordx4 %[r21], %[p], off offset:1296 sc0 sc1\n\t"
          "global_load_dwordx4 %[r22], %[p], off offset:1408 sc0 sc1\n\t"
          "global_load_dwordx4 %[r23], %[p], off offset:1424 sc0 sc1\n\t"
          "global_load_dwordx4 %[r24], %[p], off offset:1536 sc0 sc1\n\t"
          "global_load_dwordx4 %[r25], %[p], off offset:1552 sc0 sc1\n\t"
          "global_load_dwordx4 %[r26], %[p], off offset:1664 sc0 sc1\n\t"
          "global_load_dwordx4 %[r27], %[p], off offset:1680 sc0 sc1\n\t"
          "global_load_dwordx4 %[r28], %[p], off offset:1792 sc0 sc1\n\t"
          "global_load_dwordx4 %[r29], %[p], off offset:1808 sc0 sc1\n\t"
          "global_load_dwordx4 %[r30], %[p], off offset:1920 sc0 sc1\n\t"
          "global_load_dwordx4 %[r31], %[p], off offset:1936 sc0 sc1\n\t"
          "s_waitcnt vmcnt(0)"
          : [r0]"=&v"(rc0.s), [r1]"=&v"(rc1.s), [r2]"=&v"(rc2.s),
            [r3]"=&v"(rc3.s), [r4]"=&v"(rc4.s), [r5]"=&v"(rc5.s),
            [r6]"=&v"(rc6.s), [r7]"=&v"(rc7.s), [r8]"=&v"(rc8.s),
            [r9]"=&v"(rc9.s), [r10]"=&v"(rc10.s), [r11]"=&v"(rc11.s),
            [r12]"=&v"(rc12.s), [r13]"=&v"(rc13.s), [r14]"=&v"(rc14.s),
            [r15]"=&v"(rc15.s), [r16]"=&v"(rc16.s), [r17]"=&v"(rc17.s),
            [r18]"=&v"(rc18.s), [r19]"=&v"(rc19.s), [r20]"=&v"(rc20.s),
            [r21]"=&v"(rc21.s), [r22]"=&v"(rc22.s), [r23]"=&v"(rc23.s),
            [r24]"=&v"(rc24.s), [r25]"=&v"(rc25.s), [r26]"=&v"(rc26.s),
            [r27]"=&v"(rc27.s), [r28]"=&v"(rc28.s), [r29]"=&v"(rc29.s),
            [r30]"=&v"(rc30.s), [r31]"=&v"(rc31.s)
          : [p]"v"(rb)
          : "memory");
        const unsigned int bad =
            (rc0.w[2] ^ tgt) | (rc1.w[2] ^ tgt) | (rc2.w[2] ^ tgt) |
            (rc3.w[2] ^ tgt) | (rc4.w[2] ^ tgt) | (rc5.w[2] ^ tgt) |
            (rc6.w[2] ^ tgt) | (rc7.w[2] ^ tgt) | (rc8.w[2] ^ tgt) |
            (rc9.w[2] ^ tgt) | (rc10.w[2] ^ tgt) | (rc11.w[2] ^ tgt) |
            (rc12.w[2] ^ tgt) | (rc13.w[2] ^ tgt) | (rc14.w[2] ^ tgt) |
            (rc15.w[2] ^ tgt) | (rc16.w[2] ^ tgt) | (rc17.w[2] ^ tgt) |
            (rc18.w[2] ^ tgt) | (rc19.w[2] ^ tgt) | (rc20.w[2] ^ tgt) |
            (rc21.w[2] ^ tgt) | (rc22.w[2] ^ tgt) | (rc23.w[2] ^ tgt) |
            (rc24.w[2] ^ tgt) | (rc25.w[2] ^ tgt) | (rc26.w[2] ^ tgt) |
            (rc27.w[2] ^ tgt) | (rc28.w[2] ^ tgt) | (rc29.w[2] ^ tgt) |
            (rc30.w[2] ^ tgt) | (rc31.w[2] ^ tgt);
        if (__all((int)(bad == 0u))) break;
        // cheap spin: dense producer flags of this cohort (2 lines/wave)
        unsigned int v;
        do {
          v = __hip_atomic_load(&flags[(rc << 6) + lane], __ATOMIC_RELAXED,
                                __HIP_MEMORY_SCOPE_SYSTEM);
        } while (!__all((int)(v >= tgt)));
      }

#define HSTEP(KS, RA, RB)                                                      \
      {                                                                        \
        U128 a_; a_.u[0] = RA.u[0]; a_.u[1] = RB.u[0];                         \
        const int k0_ = (KS) * 32 + kb8;                                       \
        short8 b0_ = *(const short8*)((const char*)Wl + wl_byte(lane & 15, k0_)); \
        short8 b1_ = *(const short8*)((const char*)Wl + wl_byte(16 + (lane & 15), k0_)); \
        acc0 = __builtin_amdgcn_mfma_f32_16x16x32_bf16(b0_, a_.s, acc0, 0, 0, 0); \
        acc1 = __builtin_amdgcn_mfma_f32_16x16x32_bf16(b1_, a_.s, acc1, 0, 0, 0); \
      }
      HSTEP(0, rc0, rc1)   HSTEP(1, rc2, rc3)   HSTEP(2, rc4, rc5)
      HSTEP(3, rc6, rc7)   HSTEP(4, rc8, rc9)   HSTEP(5, rc10, rc11)
      HSTEP(6, rc12, rc13) HSTEP(7, rc14, rc15) HSTEP(8, rc16, rc17)
      HSTEP(9, rc18, rc19) HSTEP(10, rc20, rc21) HSTEP(11, rc22, rc23)
      HSTEP(12, rc24, rc25) HSTEP(13, rc26, rc27) HSTEP(14, rc28, rc29)
      HSTEP(15, rc30, rc31)
#undef HSTEP
    }

    // ---- epilogue: exchange f<->i / g<->o halves across lane^32 ----
    f32x4 x0, x1;
#pragma unroll
    for (int j = 0; j < 4; ++j) {
      x0[j] = __shfl_xor(acc0[j], 32);
      x1[j] = __shfl_xor(acc1[j], 32);
    }
    const bool lo = (q < 2);
    float hv[4];
#pragma unroll
    for (int r = 0; r < 4; ++r) {
      const float sF = (lo ? acc0[r] : x0[r]) + bF4[r];
      const float sI = (lo ? x0[r] : acc0[r]) + bI4[r];
      const float sG = (lo ? acc1[r] : x1[r]) + bG4[r];
      const float sO = (lo ? x1[r] : acc1[r]) + bO4[r];
      const float fg = sigm(sF);
      const float ig = sigm(sI);
      const float gg = tanh_(sG);
      const float og = sigm(sO);
      const float cn = cst[r] * fg + gg * ig;
      cst[r] = cn;
      hv[r] = og * tanh_(cn);
    }

    // ---- tagged record broadcast FIRST (visibility-critical):
    //      {4 bf16 cols, tag=t+1, pad} in one atomic 16B store ----
    if (lo && t < S_ - 1) {
      unsigned int l32 = (unsigned int)(unsigned short)f2bf(hv[0])
                       | ((unsigned int)(unsigned short)f2bf(hv[1]) << 16);
      unsigned int h32 = (unsigned int)(unsigned short)f2bf(hv[2])
                       | ((unsigned int)(unsigned short)f2bf(hv[3]) << 16);
      U128 u;
      u.w[0] = l32; u.w[1] = h32;
      u.w[2] = (unsigned int)(t + 1); u.w[3] = 0u;
      store_b128_sys(hwr + (((rowb << 6) + cs) << 5) + (q << 4), u.s);
    }

    // ---- publish flag IMMEDIATELY: drain record stores (~0.5us), then one
    //      dense-flag store. Out-stores moved AFTER (off the protocol path). ----
    if (t < S_ - 1) {
      asm volatile("s_waitcnt vmcnt(0)" ::: "memory");
      if (lane == 0) {
        __hip_atomic_store(&flags[(rc << 6) + cs], (unsigned int)(t + 1),
                           __ATOMIC_RELAXED, __HIP_MEMORY_SCOPE_SYSTEM);
      }
    }

    if (lo) {
      // ---- out: one 16B store per lane (4 consecutive cols of row rowb) ----
      f32x4 hv4;
#pragma unroll
      for (int r = 0; r < 4; ++r) hv4[r] = hv[r];
      *(f32x4*)(out + (size_t)rowb * ((size_t)S_ * H_) + (size_t)t * H_ + colq) = hv4;
      if (t == S_ - 1) {
        f32x4 c4;
#pragma unroll
        for (int r = 0; r < 4; ++r) c4[r] = cst[r];
        *(f32x4*)(out + (size_t)B_ * S_ * H_ + (size_t)rowb * H_ + colq) = hv4;
        *(f32x4*)(out + (size_t)B_ * S_ * H_ + (size_t)B_ * H_
                      + (size_t)rowb * H_ + colq) = c4;
      }
    }
  }
}

extern "C" void kernel_launch(void* const* d_in, const int* in_sizes, int n_in,
                              void* d_out, int out_size, void* d_ws, size_t ws_size,
                              hipStream_t stream) {
  (void)in_sizes; (void)n_in; (void)out_size; (void)ws_size;
  const float* x  = (const float*)d_in[0];
  const float* Wf = (const float*)d_in[1];
  const float* bf = (const float*)d_in[2];
  const float* Wi = (const float*)d_in[3];
  const float* bi = (const float*)d_in[4];
  const float* Wc = (const float*)d_in[5];
  const float* bc = (const float*)d_in[6];
  const float* Wo = (const float*)d_in[7];
  const float* bo = (const float*)d_in[8];
  float* out = (float*)d_out;

  unsigned int* flags = (unsigned int*)d_ws;   // 1 KB used: [4][64] u32
  char* hbc = (char*)d_ws + 4096;              // 256 KB tagged h records

  // zero flags + both record parities: tag 0 == h_0 == 0; captured in the
  // graph, so every replay starts from a clean state.
  hipMemsetAsync(d_ws, 0, 4096 + 2 * B_ * NCS * 32, stream);

  lstm_persist<<<dim3(NWG), dim3(NT), 0, stream>>>(
      x, Wf, bf, Wi, bi, Wc, bc, Wo, bo, out, hbc, flags);
}

// Round 6
// 5466.181 us; speedup vs baseline: 1.4438x; 1.1053x over previous
//
#include <hip/hip_runtime.h>
#include <hip/hip_bf16.h>

#define B_   64
#define S_   1024
#define D_   512
#define H_   512
#define NWG  256    // 1 wave per WG -> 1 per CU; 4 row-cohorts x 64 col-slices
#define NCS  64     // column slices
#define HCW  8      // h-columns per col-slice
#define NT   64

typedef __attribute__((ext_vector_type(8))) short short8;
typedef __attribute__((ext_vector_type(4))) float f32x4;

// Swizzled byte offset into the LDS W tile: [gc][k] bf16, row = 2048 B.
__device__ __forceinline__ int wl_byte(int gc, int k) {
  return ((gc << 11) + (k << 1)) ^ ((gc & 7) << 4);
}
__device__ __forceinline__ float sigm(float v) { return 1.0f / (1.0f + __expf(-v)); }
__device__ __forceinline__ float tanh_(float v) { return 1.0f - 2.0f / (__expf(2.0f * v) + 1.0f); }
__device__ __forceinline__ short f2bf(float f) {
  __hip_bfloat16 h = __float2bfloat16(f);
  short s;
  __builtin_memcpy(&s, &h, 2);
  return s;
}

union U128 { unsigned long long u[2]; unsigned int w[4]; short8 s; };

// DEVICE-scope (sc1) 16B store: bypasses the XCD-private L2 (the non-coherent
// boundary) and resolves at the on-die LLC -- NOT the system point (sc0 sc1),
// which was round-tripping every record through the far coherence point.
// Single transaction -> tag+data atomic.
__device__ __forceinline__ void store_b128_dev(void* p, short8 v) {
  asm volatile("global_store_dwordx4 %0, %1, off sc1" :: "v"(p), "v"(v) : "memory");
}

__global__ __launch_bounds__(NT, 1) void lstm_persist(
    const float* __restrict__ xg,
    const float* __restrict__ Wf, const float* __restrict__ bfv,
    const float* __restrict__ Wi, const float* __restrict__ biv,
    const float* __restrict__ Wc, const float* __restrict__ bcv,
    const float* __restrict__ Wo, const float* __restrict__ bov,
    float* __restrict__ out,
    char* __restrict__ hbc)   // [2][64 rows][64 cs][2 quads][16B] tagged records
{
  __shared__ short Wl[32 * 1024];    // 64 KB: W slice, [gc][k] bf16, swizzled

  const int tid  = threadIdx.x;
  const int wg   = blockIdx.x;
  const int cs   = wg >> 2;          // column slice 0..63
  const int rc   = wg & 3;           // row cohort 0..3 (16 batch rows)
  const int lane = tid;              // single wave

  // ---- one-time: stage this WG's W slice (transposed to [gc][k], bf16) ----
  {
    const float* Wg4[4] = {Wf, Wi, Wc, Wo};
    const int gc  = tid >> 1;        // 0..31
    const int seg = tid & 1;         // k half of 512
    const float* Wsrc = Wg4[gc >> 3];
    const int col = cs * HCW + (gc & 7);
    for (int kk = 0; kk < 512; ++kk) {
      const int k = seg * 512 + kk;
      *(short*)((char*)Wl + wl_byte(gc, k)) = f2bf(Wsrc[(size_t)k * H_ + col]);
    }
  }

  // Transposed-C lane mapping: C'[gatecol][row]; lane&15 = batch row,
  // (lane>>4)*4+reg = gatecol. q=0,2 -> cols 0-3; q=1,3 -> cols 4-7.
  const int q    = lane >> 4;        // 0..3
  const int rr   = lane & 15;        // batch row within wave tile
  const int c0   = (q & 1) << 2;     // col-quad base within slice's 8 cols
  const int colq = cs * HCW + c0;    // global col-quad base
  float bF4[4], bI4[4], bG4[4], bO4[4];
#pragma unroll
  for (int r = 0; r < 4; ++r) {
    bF4[r] = bfv[colq + r]; bI4[r] = biv[colq + r];
    bG4[r] = bcv[colq + r]; bO4[r] = bov[colq + r];
  }

  __syncthreads();                   // Wl ready (single wave; effectively free)

  // A/B fragment addressing: index = lane&15, 8 consecutive k at ks*32+q*8.
  const int rowb = (rc << 4) + rr;   // this lane's batch row
  const int kb8  = q << 3;
  const float* xbase = xg + (size_t)rowb * S_ * D_;

  float cst[4] = {0.f, 0.f, 0.f, 0.f};   // cell state: 4 cols of row rowb

  for (int t = 0; t < S_; ++t) {
    const char* hrd = hbc + (t & 1) * (B_ * NCS * 32);
    char*       hwr = hbc + ((t + 1) & 1) * (B_ * NCS * 32);

    f32x4 acc0 = {0.f, 0.f, 0.f, 0.f};   // gatecols [0,16):  f | i
    f32x4 acc1 = {0.f, 0.f, 0.f, 0.f};   // gatecols [16,32): g | o

    const float* xr = xbase + (size_t)t * D_;

    // ---- x-part first (no cross-WG dependency) ----
#pragma unroll 4
    for (int ks = 0; ks < 16; ++ks) {
      const int kx = ks * 32 + kb8;
      f32x4 f0 = *(const f32x4*)(xr + kx);
      f32x4 f1 = *(const f32x4*)(xr + kx + 4);
      short8 a;
#pragma unroll
      for (int j = 0; j < 4; ++j) { a[j] = f2bf(f0[j]); a[4 + j] = f2bf(f1[j]); }
      const int kw = 512 + kx;
      short8 b0 = *(const short8*)((const char*)Wl + wl_byte(lane & 15, kw));
      short8 b1 = *(const short8*)((const char*)Wl + wl_byte(16 + (lane & 15), kw));
      acc0 = __builtin_amdgcn_mfma_f32_16x16x32_bf16(b0, a, acc0, 0, 0, 0);
      acc1 = __builtin_amdgcn_mfma_f32_16x16x32_bf16(b1, a, acc1, 0, 0, 0);
    }

    // ---- h-part: poll tagged records directly (detection == data load).
    //      Lane needs records (rowb, cs=ks*4+q, quad 0/1) -> one base,
    //      strided 128B, all 32 in one asm block + vmcnt(0).
    //      The vmcnt(0) also drains our previous-step record stores
    //      (same-address ordering across buffer-parity reuse).
    //      DEVICE scope (sc1): resolves at the on-die LLC, not system. ----
    {
      const char* rb = hrd + (((rowb << 6) + q) << 5);
      const unsigned int tgt = (unsigned int)t;
      U128 rc0, rc1, rc2, rc3, rc4, rc5, rc6, rc7,
           rc8, rc9, rc10, rc11, rc12, rc13, rc14, rc15,
           rc16, rc17, rc18, rc19, rc20, rc21, rc22, rc23,
           rc24, rc25, rc26, rc27, rc28, rc29, rc30, rc31;
      while (true) {
        asm volatile(
          "global_load_dwordx4 %[r0], %[p], off sc1\n\t"
          "global_load_dwordx4 %[r1], %[p], off offset:16 sc1\n\t"
          "global_load_dwordx4 %[r2], %[p], off offset:128 sc1\n\t"
          "global_load_dwordx4 %[r3], %[p], off offset:144 sc1\n\t"
          "global_load_dwordx4 %[r4], %[p], off offset:256 sc1\n\t"
          "global_load_dwordx4 %[r5], %[p], off offset:272 sc1\n\t"
          "global_load_dwordx4 %[r6], %[p], off offset:384 sc1\n\t"
          "global_load_dwordx4 %[r7], %[p], off offset:400 sc1\n\t"
          "global_load_dwordx4 %[r8], %[p], off offset:512 sc1\n\t"
          "global_load_dwordx4 %[r9], %[p], off offset:528 sc1\n\t"
          "global_load_dwordx4 %[r10], %[p], off offset:640 sc1\n\t"
          "global_load_dwordx4 %[r11], %[p], off offset:656 sc1\n\t"
          "global_load_dwordx4 %[r12], %[p], off offset:768 sc1\n\t"
          "global_load_dwordx4 %[r13], %[p], off offset:784 sc1\n\t"
          "global_load_dwordx4 %[r14], %[p], off offset:896 sc1\n\t"
          "global_load_dwordx4 %[r15], %[p], off offset:912 sc1\n\t"
          "global_load_dwordx4 %[r16], %[p], off offset:1024 sc1\n\t"
          "global_load_dwordx4 %[r17], %[p], off offset:1040 sc1\n\t"
          "global_load_dwordx4 %[r18], %[p], off offset:1152 sc1\n\t"
          "global_load_dwordx4 %[r19], %[p], off offset:1168 sc1\n\t"
          "global_load_dwordx4 %[r20], %[p], off offset:1280 sc1\n\t"
          "global_load_dwordx4 %[r21], %[p], off offset:1296 sc1\n\t"
          "global_load_dwordx4 %[r22], %[p], off offset:1408 sc1\n\t"
          "global_load_dwordx4 %[r23], %[p], off offset:1424 sc1\n\t"
          "global_load_dwordx4 %[r24], %[p], off offset:1536 sc1\n\t"
          "global_load_dwordx4 %[r25], %[p], off offset:1552 sc1\n\t"
          "global_load_dwordx4 %[r26], %[p], off offset:1664 sc1\n\t"
          "global_load_dwordx4 %[r27], %[p], off offset:1680 sc1\n\t"
          "global_load_dwordx4 %[r28], %[p], off offset:1792 sc1\n\t"
          "global_load_dwordx4 %[r29], %[p], off offset:1808 sc1\n\t"
          "global_load_dwordx4 %[r30], %[p], off offset:1920 sc1\n\t"
          "global_load_dwordx4 %[r31], %[p], off offset:1936 sc1\n\t"
          "s_waitcnt vmcnt(0)"
          : [r0]"=&v"(rc0.s), [r1]"=&v"(rc1.s), [r2]"=&v"(rc2.s),
            [r3]"=&v"(rc3.s), [r4]"=&v"(rc4.s), [r5]"=&v"(rc5.s),
            [r6]"=&v"(rc6.s), [r7]"=&v"(rc7.s), [r8]"=&v"(rc8.s),
            [r9]"=&v"(rc9.s), [r10]"=&v"(rc10.s), [r11]"=&v"(rc11.s),
            [r12]"=&v"(rc12.s), [r13]"=&v"(rc13.s), [r14]"=&v"(rc14.s),
            [r15]"=&v"(rc15.s), [r16]"=&v"(rc16.s), [r17]"=&v"(rc17.s),
            [r18]"=&v"(rc18.s), [r19]"=&v"(rc19.s), [r20]"=&v"(rc20.s),
            [r21]"=&v"(rc21.s), [r22]"=&v"(rc22.s), [r23]"=&v"(rc23.s),
            [r24]"=&v"(rc24.s), [r25]"=&v"(rc25.s), [r26]"=&v"(rc26.s),
            [r27]"=&v"(rc27.s), [r28]"=&v"(rc28.s), [r29]"=&v"(rc29.s),
            [r30]"=&v"(rc30.s), [r31]"=&v"(rc31.s)
          : [p]"v"(rb)
          : "memory");
        const unsigned int bad =
            (rc0.w[2] ^ tgt) | (rc1.w[2] ^ tgt) | (rc2.w[2] ^ tgt) |
            (rc3.w[2] ^ tgt) | (rc4.w[2] ^ tgt) | (rc5.w[2] ^ tgt) |
            (rc6.w[2] ^ tgt) | (rc7.w[2] ^ tgt) | (rc8.w[2] ^ tgt) |
            (rc9.w[2] ^ tgt) | (rc10.w[2] ^ tgt) | (rc11.w[2] ^ tgt) |
            (rc12.w[2] ^ tgt) | (rc13.w[2] ^ tgt) | (rc14.w[2] ^ tgt) |
            (rc15.w[2] ^ tgt) | (rc16.w[2] ^ tgt) | (rc17.w[2] ^ tgt) |
            (rc18.w[2] ^ tgt) | (rc19.w[2] ^ tgt) | (rc20.w[2] ^ tgt) |
            (rc21.w[2] ^ tgt) | (rc22.w[2] ^ tgt) | (rc23.w[2] ^ tgt) |
            (rc24.w[2] ^ tgt) | (rc25.w[2] ^ tgt) | (rc26.w[2] ^ tgt) |
            (rc27.w[2] ^ tgt) | (rc28.w[2] ^ tgt) | (rc29.w[2] ^ tgt) |
            (rc30.w[2] ^ tgt) | (rc31.w[2] ^ tgt);
        if (__all((int)(bad == 0u))) break;
      }

#define HSTEP(KS, RA, RB)                                                      \
      {                                                                        \
        U128 a_; a_.u[0] = RA.u[0]; a_.u[1] = RB.u[0];                         \
        const int k0_ = (KS) * 32 + kb8;                                       \
        short8 b0_ = *(const short8*)((const char*)Wl + wl_byte(lane & 15, k0_)); \
        short8 b1_ = *(const short8*)((const char*)Wl + wl_byte(16 + (lane & 15), k0_)); \
        acc0 = __builtin_amdgcn_mfma_f32_16x16x32_bf16(b0_, a_.s, acc0, 0, 0, 0); \
        acc1 = __builtin_amdgcn_mfma_f32_16x16x32_bf16(b1_, a_.s, acc1, 0, 0, 0); \
      }
      HSTEP(0, rc0, rc1)   HSTEP(1, rc2, rc3)   HSTEP(2, rc4, rc5)
      HSTEP(3, rc6, rc7)   HSTEP(4, rc8, rc9)   HSTEP(5, rc10, rc11)
      HSTEP(6, rc12, rc13) HSTEP(7, rc14, rc15) HSTEP(8, rc16, rc17)
      HSTEP(9, rc18, rc19) HSTEP(10, rc20, rc21) HSTEP(11, rc22, rc23)
      HSTEP(12, rc24, rc25) HSTEP(13, rc26, rc27) HSTEP(14, rc28, rc29)
      HSTEP(15, rc30, rc31)
#undef HSTEP
    }

    // ---- epilogue: exchange f<->i / g<->o halves across lane^32 ----
    f32x4 x0, x1;
#pragma unroll
    for (int j = 0; j < 4; ++j) {
      x0[j] = __shfl_xor(acc0[j], 32);
      x1[j] = __shfl_xor(acc1[j], 32);
    }
    const bool lo = (q < 2);
    float hv[4];
#pragma unroll
    for (int r = 0; r < 4; ++r) {
      const float sF = (lo ? acc0[r] : x0[r]) + bF4[r];
      const float sI = (lo ? x0[r] : acc0[r]) + bI4[r];
      const float sG = (lo ? acc1[r] : x1[r]) + bG4[r];
      const float sO = (lo ? x1[r] : acc1[r]) + bO4[r];
      const float fg = sigm(sF);
      const float ig = sigm(sI);
      const float gg = tanh_(sG);
      const float og = sigm(sO);
      const float cn = cst[r] * fg + gg * ig;
      cst[r] = cn;
      hv[r] = og * tanh_(cn);
    }

    if (lo) {
      // ---- tagged record broadcast FIRST (visibility-critical):
      //      {4 bf16 cols, tag=t+1, pad} in one atomic 16B store ----
      if (t < S_ - 1) {
        unsigned int l32 = (unsigned int)(unsigned short)f2bf(hv[0])
                         | ((unsigned int)(unsigned short)f2bf(hv[1]) << 16);
        unsigned int h32 = (unsigned int)(unsigned short)f2bf(hv[2])
                         | ((unsigned int)(unsigned short)f2bf(hv[3]) << 16);
        U128 u;
        u.w[0] = l32; u.w[1] = h32;
        u.w[2] = (unsigned int)(t + 1); u.w[3] = 0u;
        store_b128_dev(hwr + (((rowb << 6) + cs) << 5) + (q << 4), u.s);
      }

      // ---- out: one 16B store per lane (4 consecutive cols of row rowb) ----
      f32x4 hv4;
#pragma unroll
      for (int r = 0; r < 4; ++r) hv4[r] = hv[r];
      *(f32x4*)(out + (size_t)rowb * ((size_t)S_ * H_) + (size_t)t * H_ + colq) = hv4;
      if (t == S_ - 1) {
        f32x4 c4;
#pragma unroll
        for (int r = 0; r < 4; ++r) c4[r] = cst[r];
        *(f32x4*)(out + (size_t)B_ * S_ * H_ + (size_t)rowb * H_ + colq) = hv4;
        *(f32x4*)(out + (size_t)B_ * S_ * H_ + (size_t)B_ * H_
                      + (size_t)rowb * H_ + colq) = c4;
      }
    }
    // No drain, no flag, no barrier: tags ride with the data.
  }
}

extern "C" void kernel_launch(void* const* d_in, const int* in_sizes, int n_in,
                              void* d_out, int out_size, void* d_ws, size_t ws_size,
                              hipStream_t stream) {
  (void)in_sizes; (void)n_in; (void)out_size; (void)ws_size;
  const float* x  = (const float*)d_in[0];
  const float* Wf = (const float*)d_in[1];
  const float* bf = (const float*)d_in[2];
  const float* Wi = (const float*)d_in[3];
  const float* bi = (const float*)d_in[4];
  const float* Wc = (const float*)d_in[5];
  const float* bc = (const float*)d_in[6];
  const float* Wo = (const float*)d_in[7];
  const float* bo = (const float*)d_in[8];
  float* out = (float*)d_out;

  char* hbc = (char*)d_ws;   // 256 KB: [2][64][64][2][16B] tagged h records

  // zero both parities: tag 0 == h_0 == 0; captured in the graph, so every
  // replay starts from a clean state. (Kernel-dispatch boundary writes back
  // L2, so sc1 loads see the memset.)
  hipMemsetAsync(d_ws, 0, 2 * B_ * NCS * 32, stream);

  lstm_persist<<<dim3(NWG), dim3(NT), 0, stream>>>(
      x, Wf, bf, Wi, bi, Wc, bc, Wo, bo, out, hbc);
}